// Round 1
// baseline (531.915 us; speedup 1.0000x reference)
//
#include <hip/hip_runtime.h>

// x[B,S,V] -> out[B,S,V,D] = relu(LN_D(x*W[v]+b[v]) * gamma[v] + beta[v])
// B=16,S=2048,V=32,D=128. Output 537MB fp32 => pure write-BW problem.
// Write roofline: 537MB / 6.3TB/s ~= 85-95us kernel time.
//
// Closed-form LN (h_d affine in x):
//   out_d = relu( (x*(W_d-mW) + (b_d-mb)) * gamma_d * rsqrt(x^2 p2 + x p1 + p0) + beta_d )
//   p2=Var(W), p1=2Cov(W,b), p0=Var(b)+eps.
//
// Structure: each thread owns a fixed (v, d4) -> params live in REGISTERS for
// the whole kernel. Shuffle reduction computes LN stats in-register (no
// precompute kernel, no workspace).
//
// R2 change (store path): the harness's fillBuffer proves 6.29 TB/s pure-write
// BW with PLAIN cache-allocating dwordx4 stores at 10% occupancy. Our kernel
// (inferred ~3 TB/s) differed in one structural way: nontemporal (`nt`,
// L2 no-allocate) stores. Drop the nt hint (L2 holds nothing valuable here
// anyway) and deepen unroll 4->8 for more stores/loads in flight per wave.

#define EPS 1e-5f

constexpr int D = 128;
constexpr int V = 32;
constexpr int BS_TOTAL = 16 * 2048;   // 32768 (b,s) rows
constexpr int NB = 512;               // blocks per v-group (4 groups -> 2048 blocks = 8/CU)
constexpr int CHUNK = BS_TOTAL / NB;  // 64 contiguous rows per block

typedef float vfloat4 __attribute__((ext_vector_type(4)));

__global__ __launch_bounds__(256) void fused_kernel(
    const float* __restrict__ x,
    const float* __restrict__ W,
    const float* __restrict__ Bv,
    const float* __restrict__ G,
    const float* __restrict__ Beta,
    float* __restrict__ out) {
  const int t = threadIdx.x;
  const int d4 = t & 31;              // float4 column within D
  const int vl = t >> 5;              // 0..7 local variable index
  const int group = blockIdx.x & 3;   // which 8-variable group
  const int blk = blockIdx.x >> 2;    // 0..NB-1 row chunk
  const int v = group * 8 + vl;

  // ---- one-time param setup, all in registers ----
  const int pidx = v * (D / 4) + d4;
  const vfloat4 w4  = reinterpret_cast<const vfloat4*>(W)[pidx];
  const vfloat4 b4  = reinterpret_cast<const vfloat4*>(Bv)[pidx];
  const vfloat4 g4  = reinterpret_cast<const vfloat4*>(G)[pidx];
  const vfloat4 be4 = reinterpret_cast<const vfloat4*>(Beta)[pidx];

  // mean over D: reduce across the 32 lanes sharing v (xor masks <=16 stay
  // inside each 32-lane half of the wave64)
  float sw = w4.x + w4.y + w4.z + w4.w;
  float sb = b4.x + b4.y + b4.z + b4.w;
  #pragma unroll
  for (int off = 16; off > 0; off >>= 1) {
    sw += __shfl_xor(sw, off);
    sb += __shfl_xor(sb, off);
  }
  const float mW = sw * (1.0f / D);
  const float mB = sb * (1.0f / D);

  vfloat4 a4 = w4 - mW;   // centered (unscaled) W
  vfloat4 c4 = b4 - mB;   // centered (unscaled) b

  float sww = a4.x * a4.x + a4.y * a4.y + a4.z * a4.z + a4.w * a4.w;
  float swb = a4.x * c4.x + a4.y * c4.y + a4.z * c4.z + a4.w * c4.w;
  float sbb = c4.x * c4.x + c4.y * c4.y + c4.z * c4.z + c4.w * c4.w;
  #pragma unroll
  for (int off = 16; off > 0; off >>= 1) {
    sww += __shfl_xor(sww, off);
    swb += __shfl_xor(swb, off);
    sbb += __shfl_xor(sbb, off);
  }
  const float p2 = sww * (1.0f / D);
  const float p1 = 2.0f * swb * (1.0f / D);
  const float p0 = sbb * (1.0f / D) + EPS;

  // fold gamma into the affine terms
  a4 *= g4;
  c4 *= g4;

  // ---- streaming loop over 64 contiguous (b,s) rows ----
  const int bs0 = blk * CHUNK;
  vfloat4* op = reinterpret_cast<vfloat4*>(out);

  #pragma unroll 8
  for (int i = 0; i < CHUNK; ++i) {
    const int row = (bs0 + i) * V + v;           // (b,s,v) flat row
    const float xv = x[row];                     // broadcast across 32 lanes
    const float r = rsqrtf(fmaf(xv, fmaf(xv, p2, p1), p0));

    vfloat4 o;
    o.x = fmaxf(fmaf(fmaf(xv, a4.x, c4.x), r, be4.x), 0.0f);
    o.y = fmaxf(fmaf(fmaf(xv, a4.y, c4.y), r, be4.y), 0.0f);
    o.z = fmaxf(fmaf(fmaf(xv, a4.z, c4.z), r, be4.z), 0.0f);
    o.w = fmaxf(fmaf(fmaf(xv, a4.w, c4.w), r, be4.w), 0.0f);

    // plain cache-allocating store (match fillBuffer's 6.29 TB/s path)
    op[row * (D / 4) + d4] = o;
  }
}

extern "C" void kernel_launch(void* const* d_in, const int* in_sizes, int n_in,
                              void* d_out, int out_size, void* d_ws, size_t ws_size,
                              hipStream_t stream) {
  const float* x     = (const float*)d_in[0];
  const float* W     = (const float*)d_in[1];
  const float* b     = (const float*)d_in[2];
  const float* gamma = (const float*)d_in[3];
  const float* beta  = (const float*)d_in[4];
  float* out = (float*)d_out;

  fused_kernel<<<4 * NB, 256, 0, stream>>>(x, W, b, gamma, beta, out);
}

// Round 2
// 531.388 us; speedup vs baseline: 1.0010x; 1.0010x over previous
//
#include <hip/hip_runtime.h>

// x[B,S,V] -> out[B,S,V,D] = relu(LN_D(x*W[v]+b[v]) * gamma[v] + beta[v])
// B=16,S=2048,V=32,D=128. Output 537MB fp32 => pure write-BW problem.
// Write roofline: 537MB / 6.24TB/s (fillBuffer-demonstrated) ~= 86us kernel.
//
// Closed-form LN (h_d affine in x):
//   out_d = relu( (x*(W_d-mW) + (b_d-mb)) * gamma_d * rsqrt(x^2 p2 + x p1 + p0) + beta_d )
//   p2=Var(W), p1=2Cov(W,b), p0=Var(b)+eps.
//
// R2 decomposition: timed region = poison-fill(344us) + kernel. R0(nt)=176us,
// R1(plain)=188us kernel component => ~2.9 TB/s, 2x off the fill's 6.24 TB/s.
// R1 falsified the nt-store theory. Remaining structural differences vs fill:
//   (a) per-block store stream was 4KB-chunk/16KB-stride (8-variable slice),
//   (b) stream loop began with a cold global x load feeding rsqrt feeding
//       the stores.
// R3 kernel: block owns ALL 32 variables for 32 contiguous rows -> one
// perfectly contiguous ascending 512KB store stream per block (identical
// shape to fillBuffer), and x staged to LDS once (4KB, one float4/thread)
// so the stream loop has ZERO global loads. Each thread carries params for
// 4 variables (v = vl+8k) in registers (~60 VGPRs).

#define EPS 1e-5f

constexpr int D = 128;
constexpr int V = 32;
constexpr int BS_TOTAL = 16 * 2048;              // 32768 (b,s) rows
constexpr int ROWS = 32;                         // rows per block
constexpr int NBLK = BS_TOTAL / ROWS;            // 1024 blocks = 4/CU
constexpr int K = 4;                             // variables per thread

typedef float vfloat4 __attribute__((ext_vector_type(4)));

__global__ __launch_bounds__(256) void fused_kernel(
    const float* __restrict__ x,
    const float* __restrict__ W,
    const float* __restrict__ Bv,
    const float* __restrict__ G,
    const float* __restrict__ Beta,
    float* __restrict__ out) {
  const int t = threadIdx.x;
  const int d4 = t & 31;              // float4 column within D
  const int vl = t >> 5;              // 0..7; thread's variables are vl+8k

  __shared__ float xs[ROWS * V];      // 4 KB of x for this block

  // ---- stage x: one coalesced float4 per thread (block's 4KB chunk) ----
  {
    const vfloat4 xv4 =
        reinterpret_cast<const vfloat4*>(x + (size_t)blockIdx.x * (ROWS * V))[t];
    reinterpret_cast<vfloat4*>(xs)[t] = xv4;
  }

  // ---- one-time param setup for K=4 variables, all in registers ----
  vfloat4 a4[K], c4[K], be4[K];
  float p2[K], p1[K], p0[K];

  #pragma unroll
  for (int k = 0; k < K; ++k) {
    const int v = vl + 8 * k;
    const int pidx = v * (D / 4) + d4;
    const vfloat4 w4 = reinterpret_cast<const vfloat4*>(W)[pidx];
    const vfloat4 b4 = reinterpret_cast<const vfloat4*>(Bv)[pidx];
    const vfloat4 g4 = reinterpret_cast<const vfloat4*>(G)[pidx];
    be4[k] = reinterpret_cast<const vfloat4*>(Beta)[pidx];

    // mean over D: reduce across the 32 lanes sharing v (xor off<=16 stays
    // inside each 32-lane half of the wave64)
    float sw = w4.x + w4.y + w4.z + w4.w;
    float sb = b4.x + b4.y + b4.z + b4.w;
    #pragma unroll
    for (int off = 16; off > 0; off >>= 1) {
      sw += __shfl_xor(sw, off);
      sb += __shfl_xor(sb, off);
    }
    const float mW = sw * (1.0f / D);
    const float mB = sb * (1.0f / D);

    vfloat4 a = w4 - mW;
    vfloat4 c = b4 - mB;

    float sww = a.x * a.x + a.y * a.y + a.z * a.z + a.w * a.w;
    float swb = a.x * c.x + a.y * c.y + a.z * c.z + a.w * c.w;
    float sbb = c.x * c.x + c.y * c.y + c.z * c.z + c.w * c.w;
    #pragma unroll
    for (int off = 16; off > 0; off >>= 1) {
      sww += __shfl_xor(sww, off);
      swb += __shfl_xor(swb, off);
      sbb += __shfl_xor(sbb, off);
    }
    p2[k] = sww * (1.0f / D);
    p1[k] = 2.0f * swb * (1.0f / D);
    p0[k] = sbb * (1.0f / D) + EPS;
    a4[k] = a * g4;                   // fold gamma in
    c4[k] = c * g4;
  }

  __syncthreads();

  // ---- streaming loop: pure {ds_read broadcast -> VALU -> nt store} ----
  // Block writes op[0 .. 32*32*32) float4 = 512KB contiguous ascending.
  vfloat4* op = reinterpret_cast<vfloat4*>(out) +
                (size_t)blockIdx.x * (ROWS * V * (D / 4));

  #pragma unroll 4
  for (int i = 0; i < ROWS; ++i) {
    #pragma unroll
    for (int k = 0; k < K; ++k) {
      const int v = vl + 8 * k;
      const float xv = xs[i * V + v];               // LDS broadcast
      const float r = rsqrtf(fmaf(xv, fmaf(xv, p2[k], p1[k]), p0[k]));

      vfloat4 o;
      o.x = fmaxf(fmaf(fmaf(xv, a4[k].x, c4[k].x), r, be4[k].x), 0.0f);
      o.y = fmaxf(fmaf(fmaf(xv, a4[k].y, c4[k].y), r, be4[k].y), 0.0f);
      o.z = fmaxf(fmaf(fmaf(xv, a4[k].z, c4[k].z), r, be4[k].z), 0.0f);
      o.w = fmaxf(fmaf(fmaf(xv, a4[k].w, c4[k].w), r, be4[k].w), 0.0f);

      // wave-store = 1KB contiguous; block-aggregate = linear stream
      __builtin_nontemporal_store(o, op + i * (V * D / 4) + v * (D / 4) + d4);
    }
  }
}

extern "C" void kernel_launch(void* const* d_in, const int* in_sizes, int n_in,
                              void* d_out, int out_size, void* d_ws, size_t ws_size,
                              hipStream_t stream) {
  const float* x     = (const float*)d_in[0];
  const float* W     = (const float*)d_in[1];
  const float* b     = (const float*)d_in[2];
  const float* gamma = (const float*)d_in[3];
  const float* beta  = (const float*)d_in[4];
  float* out = (float*)d_out;

  fused_kernel<<<NBLK, 256, 0, stream>>>(x, W, b, gamma, beta, out);
}